// Round 2
// baseline (341.483 us; speedup 1.0000x reference)
//
#include <hip/hip_runtime.h>
#include <stdint.h>

#define HW 3136      // 56*56
#define K_SEL 313    // int(0.1*3136)
#define NTH 256
#define RPB 4        // rows per block = one row per wave; NO __syncthreads anywhere
#define NROWS 16384  // 64*256
#define NBLK (NROWS / RPB)
#define FAST_CAP 512

// Fast-path band: threshold = upper-0.0998 quantile of a 3136-sample N(0,1)
// row = 1.283 +/- 0.031 (1 sigma). [0.8, 1.8) is +/-16 sigma. Exact fallback
// (full 256-bin histogram) handles any row whose threshold escapes the band.
#define BAND_LO  0.8f
#define BAND_HI  1.8f
#define BAND_INV 128.0f   // 128 bins over [0.8, 1.8)

__device__ __forceinline__ uint32_t f2k(float f) {
    uint32_t u = __float_as_uint(f);
    return (u & 0x80000000u) ? ~u : (u | 0x80000000u);
}
// 256-bin map over [-4,4): clamp((int)((x+4)*32), 0, 255); trunc==floor for x>=-4
__device__ __forceinline__ int binOf(float x) {
    int b = (int)((x + 4.0f) * 32.0f);
    return min(255, max(0, b));
}
// band bin for x >= BAND_LO: 0..127 inside band, 128 = overflow (>= HI). Monotone.
__device__ __forceinline__ int bandBin(float x) {
    return (x >= BAND_HI) ? 128 : min(127, (int)((x - BAND_LO) * BAND_INV));
}

__global__ __launch_bounds__(NTH, 4) void wta2d_kernel(const float* __restrict__ x,
                                                       float* __restrict__ out) {
    // All LDS is partitioned per wave; waves never synchronize with each other.
    __shared__ int      histF[RPB][132];       // 129 used (128 band bins + overflow)
    __shared__ uint32_t cand[RPB][FAST_CAP];   // fast cands; fallback reuses as 256-bin hist
    __shared__ int      wbin[RPB], wk2[RPB], wm[RPB];
    __shared__ uint32_t wtkey[RPB];

    const int tid  = threadIdx.x;
    const int wave = tid >> 6;
    const int lane = tid & 63;
    const int row  = blockIdx.x * RPB + wave;
    const float4* xrow = (const float4*)(x + (size_t)row * HW);
    float4*       orow = (float4*)(out + (size_t)row * HW);

    // ---- zero per-wave state (wave-synchronous) ----
    histF[wave][lane]      = 0;
    histF[wave][64 + lane] = 0;
    if (lane == 0) { histF[wave][128] = 0; wbin[wave] = -1; wm[wave] = 0; }

    // ---- load the whole row into registers: 12-13 float4/lane, all in flight ----
    float4 r[13];
    #pragma unroll
    for (int j = 0; j < 12; j++) r[j] = xrow[lane + j * 64];
    if (lane < 16) r[12] = xrow[lane + 768];    // 784 = 12*64 + 16

    // ---- band-tail histogram (~21% of elements touch LDS) ----
    #pragma unroll
    for (int j = 0; j < 13; j++) {
        if (j < 12 || lane < 16) {
            float a[4] = {r[j].x, r[j].y, r[j].z, r[j].w};
            #pragma unroll
            for (int q = 0; q < 4; q++)
                if (a[q] >= BAND_LO) atomicAdd(&histF[wave][bandBin(a[q])], 1);
        }
    }
    __threadfence_block();   // order LDS ops; same-wave lockstep makes this sufficient

    // ---- suffix scan over 128 band bins within the wave (2 bins/lane, descending) ----
    {
        const int ta   = 127 - 2 * lane;            // lane0: {127,126} ... lane63: {1,0}
        const int a    = histF[wave][ta];
        const int b    = histF[wave][ta - 1];
        const int c_hi = histF[wave][128];
        int pre = a + b;
        #pragma unroll
        for (int off = 1; off < 64; off <<= 1) {
            int n = __shfl_up(pre, off, 64);
            if (lane >= off) pre += n;
        }
        const int aboveB = c_hi + pre;              // #elems >= lower edge of bin ta-1
        const int aboveA = aboveB - b;              // #elems >= lower edge of bin ta
        if (aboveA >= K_SEL && aboveA - a < K_SEL) { wbin[wave] = ta;     wk2[wave] = K_SEL - (aboveA - a); }
        if (aboveB >= K_SEL && aboveB - b < K_SEL) { wbin[wave] = ta - 1; wk2[wave] = K_SEL - (aboveB - b); }
        // threshold >= BAND_HI -> c_hi >= K -> no bin passes; threshold < BAND_LO ->
        // total above < K at bin 0 -> no bin passes. Either way wbin stays -1.
    }
    __threadfence_block();

    bool fast = (wbin[wave] >= 0);
    if (fast) {
        const int tbin = wbin[wave];
        // ---- compact target-bin candidates straight from registers ----
        #pragma unroll
        for (int j = 0; j < 13; j++) {
            if (j < 12 || lane < 16) {
                float a[4] = {r[j].x, r[j].y, r[j].z, r[j].w};
                #pragma unroll
                for (int q = 0; q < 4; q++) {
                    float xv = a[q];
                    if (xv >= BAND_LO && bandBin(xv) == tbin) {
                        int idx = atomicAdd(&wm[wave], 1);
                        if (idx < FAST_CAP) cand[wave][idx] = f2k(xv);
                    }
                }
            }
        }
        __threadfence_block();
        const int m = wm[wave];                     // ~5 expected
        if (m > FAST_CAP) {
            fast = false;                           // wave-uniform; exact fallback
        } else {
            const int k2 = wk2[wave];
            for (int j = lane; j < m; j += 64) {
                uint32_t kj = cand[wave][j];
                int gt = 0, ge = 0;
                for (int i = 0; i < m; i++) {
                    uint32_t ki = cand[wave][i];
                    gt += (ki > kj) ? 1 : 0;
                    ge += (ki >= kj) ? 1 : 0;
                }
                if (gt < k2 && ge >= k2) wtkey[wave] = kj;  // unique key
            }
            __threadfence_block();
        }
    }

    if (!fast) {
        // ======== exact fallback: full 256-bin histogram over [-4,4) ========
        // reuse cand[wave][0..255] as the histogram
        int* h = (int*)cand[wave];
        for (int bsel = lane; bsel < 256; bsel += 64) h[bsel] = 0;
        if (lane == 0) { wm[wave] = 0; wbin[wave] = -1; }
        __threadfence_block();
        #pragma unroll
        for (int j = 0; j < 13; j++) {
            if (j < 12 || lane < 16) {
                float a[4] = {r[j].x, r[j].y, r[j].z, r[j].w};
                #pragma unroll
                for (int q = 0; q < 4; q++) atomicAdd(&h[binOf(a[q])], 1);
            }
        }
        __threadfence_block();
        // suffix scan within the wave: 4 bins/lane, descending
        const int t0 = 255 - 4 * lane;
        const int g0 = h[t0], g1 = h[t0 - 1], g2 = h[t0 - 2], g3 = h[t0 - 3];
        int pre = g0 + g1 + g2 + g3;
        #pragma unroll
        for (int off = 1; off < 64; off <<= 1) {
            int n = __shfl_up(pre, off, 64);
            if (lane >= off) pre += n;
        }
        const int s3 = pre, s2v = pre - g3, s1v = s2v - g2, s0v = s1v - g1;
        if (s0v >= K_SEL && s0v - g0 < K_SEL) { wbin[wave] = t0;     wk2[wave] = K_SEL - (s0v - g0); }
        if (s1v >= K_SEL && s1v - g1 < K_SEL) { wbin[wave] = t0 - 1; wk2[wave] = K_SEL - (s1v - g1); }
        if (s2v >= K_SEL && s2v - g2 < K_SEL) { wbin[wave] = t0 - 2; wk2[wave] = K_SEL - (s2v - g2); }
        if (s3  >= K_SEL && s3  - g3 < K_SEL) { wbin[wave] = t0 - 3; wk2[wave] = K_SEL - (s3  - g3); }
        __threadfence_block();
        const int tbin = wbin[wave];
        // compact (overwrites stale hist; only slots < m are read afterwards)
        #pragma unroll
        for (int j = 0; j < 13; j++) {
            if (j < 12 || lane < 16) {
                float a[4] = {r[j].x, r[j].y, r[j].z, r[j].w};
                #pragma unroll
                for (int q = 0; q < 4; q++) {
                    if (binOf(a[q]) == tbin) {
                        int idx = atomicAdd(&wm[wave], 1);
                        if (idx < FAST_CAP) cand[wave][idx] = f2k(a[q]);
                    }
                }
            }
        }
        __threadfence_block();
        const int m2 = min(wm[wave], FAST_CAP);
        const int k2 = wk2[wave];
        for (int j = lane; j < m2; j += 64) {
            uint32_t kj = cand[wave][j];
            int gt = 0, ge = 0;
            for (int i = 0; i < m2; i++) {
                uint32_t ki = cand[wave][i];
                gt += (ki > kj) ? 1 : 0;
                ge += (ki >= kj) ? 1 : 0;
            }
            if (gt < k2 && ge >= k2) wtkey[wave] = kj;
        }
        __threadfence_block();
    }

    // ---- output straight from registers ----
    const uint32_t tk = wtkey[wave];
    const uint32_t tb = (tk & 0x80000000u) ? (tk ^ 0x80000000u) : ~tk;
    const float tval = __uint_as_float(tb);
    #pragma unroll
    for (int j = 0; j < 12; j++) {
        float4 v = r[j];
        float4 o;
        o.x = (v.x < tval) ? v.x : 0.0f;
        o.y = (v.y < tval) ? v.y : 0.0f;
        o.z = (v.z < tval) ? v.z : 0.0f;
        o.w = (v.w < tval) ? v.w : 0.0f;
        orow[lane + j * 64] = o;
    }
    if (lane < 16) {
        float4 v = r[12];
        float4 o;
        o.x = (v.x < tval) ? v.x : 0.0f;
        o.y = (v.y < tval) ? v.y : 0.0f;
        o.z = (v.z < tval) ? v.z : 0.0f;
        o.w = (v.w < tval) ? v.w : 0.0f;
        orow[lane + 768] = o;
    }
}

extern "C" void kernel_launch(void* const* d_in, const int* in_sizes, int n_in,
                              void* d_out, int out_size, void* d_ws, size_t ws_size,
                              hipStream_t stream) {
    const float* x = (const float*)d_in[0];
    float* out = (float*)d_out;
    wta2d_kernel<<<NBLK, NTH, 0, stream>>>(x, out);
}